// Round 1
// baseline (1993.697 us; speedup 1.0000x reference)
//
#include <hip/hip_runtime.h>
#include <hip/hip_bf16.h>

// Problem constants (match reference setup_inputs)
//   U=100000, NI=50000, NB=20000, D=64
//   NNZ_UI=2M, NNZ_BI=1M, NNZ_UB=1M
// Output packing rows: [UI_u(U) | UB_u(U) | BI_b(NB) | UB_b(NB) | UI_i(NI) | BI_i(NI)]

#define D 64

// One lane per (edge, dim). e is wave-uniform (64 lanes per edge).
// src row c: if c < nA read A[c], else B[c-nA]. Layer-2 call passes A=B=f1, nA=n_total.
__global__ void scatter_spmm(const int* __restrict__ rows, const int* __restrict__ cols,
                             const float* __restrict__ vals,
                             const float* __restrict__ A, const float* __restrict__ B,
                             int nA, int E, float* __restrict__ out) {
    long long t = (long long)blockIdx.x * blockDim.x + threadIdx.x;
    int e = (int)(t >> 6);
    int d = (int)(t & 63);
    if (e >= E) return;
    int r = rows[e];
    int c = cols[e];
    float v = vals[e];
    const float* src = (c < nA) ? (A + (long long)c * D) : (B + (long long)(c - nA) * D);
    atomicAdd(&out[(long long)r * D + d], v * src[d]);
}

// One wave per row: L2-normalize f1,f2 across the 64 dims via shuffle reduction,
// combine with layer-0 feat, write into packed output location.
__global__ void finalize_rows(const float* __restrict__ A, const float* __restrict__ B,
                              int nA, int n_total,
                              const float* __restrict__ f1, const float* __restrict__ f2,
                              float* __restrict__ out, long long outOffA, long long outOffB) {
    long long t = (long long)blockIdx.x * blockDim.x + threadIdx.x;
    int i = (int)(t >> 6);
    int d = (int)(t & 63);
    if (i >= n_total) return;
    float x0 = (i < nA) ? A[(long long)i * D + d] : B[(long long)(i - nA) * D + d];
    float x1 = f1[(long long)i * D + d];
    float x2 = f2[(long long)i * D + d];
    float s1 = x1 * x1;
    float s2 = x2 * x2;
    #pragma unroll
    for (int m = 32; m > 0; m >>= 1) {
        s1 += __shfl_xor(s1, m, 64);
        s2 += __shfl_xor(s2, m, 64);
    }
    float n1 = fmaxf(sqrtf(s1), 1e-12f);
    float n2 = fmaxf(sqrtf(s2), 1e-12f);
    float y = (x0 + x1 / n1 + x2 / n2) * (1.0f / 3.0f);
    long long orow = (i < nA) ? (outOffA + i) : (outOffB + (i - nA));
    out[orow * D + d] = y;
}

extern "C" void kernel_launch(void* const* d_in, const int* in_sizes, int n_in,
                              void* d_out, int out_size, void* d_ws, size_t ws_size,
                              hipStream_t stream) {
    const float* users   = (const float*)d_in[0];
    const float* items   = (const float*)d_in[1];
    const float* bundles = (const float*)d_in[2];
    const float* ui_vals = (const float*)d_in[3];
    const float* bi_vals = (const float*)d_in[4];
    const float* ub_vals = (const float*)d_in[5];
    const int* ui_rows = (const int*)d_in[6];
    const int* ui_cols = (const int*)d_in[7];
    const int* bi_rows = (const int*)d_in[8];
    const int* bi_cols = (const int*)d_in[9];
    const int* ub_rows = (const int*)d_in[10];
    const int* ub_cols = (const int*)d_in[11];

    const int U  = in_sizes[0] / D;   // 100000
    const int NI = in_sizes[1] / D;   // 50000
    const int NB = in_sizes[2] / D;   // 20000
    const int E_ui = in_sizes[3];
    const int E_bi = in_sizes[4];
    const int E_ub = in_sizes[5];

    float* out = (float*)d_out;

    // Workspace: two dense layer buffers sized for the largest propagation (U+NI rows).
    const int maxRows = U + NI;
    float* f1 = (float*)d_ws;
    float* f2 = f1 + (size_t)maxRows * D;

    // Output row offsets
    const long long off_UI_u = 0;
    const long long off_UB_u = U;                       // 100000
    const long long off_BI_b = 2LL * U;                 // 200000
    const long long off_UB_b = 2LL * U + NB;            // 220000
    const long long off_UI_i = 2LL * U + 2LL * NB;      // 240000
    const long long off_BI_i = 2LL * U + 2LL * NB + NI; // 290000

    auto run_prop = [&](const int* rows, const int* cols, const float* vals, int E,
                        const float* A, const float* B, int nA, int nB,
                        long long offA, long long offB) {
        const int n_total = nA + nB;
        const size_t bytes = (size_t)n_total * D * sizeof(float);
        const long long T = (long long)E * D;
        const int sblocks = (int)((T + 255) / 256);

        hipMemsetAsync(f1, 0, bytes, stream);
        scatter_spmm<<<sblocks, 256, 0, stream>>>(rows, cols, vals, A, B, nA, E, f1);
        hipMemsetAsync(f2, 0, bytes, stream);
        scatter_spmm<<<sblocks, 256, 0, stream>>>(rows, cols, vals, f1, f1, n_total, E, f2);

        const long long FT = (long long)n_total * D;
        const int fblocks = (int)((FT + 255) / 256);
        finalize_rows<<<fblocks, 256, 0, stream>>>(A, B, nA, n_total, f1, f2, out, offA, offB);
    };

    // UI: users + items, n_total = U+NI
    run_prop(ui_rows, ui_cols, ui_vals, E_ui, users, items, U, NI, off_UI_u, off_UI_i);
    // BI: bundles + items, n_total = NB+NI
    run_prop(bi_rows, bi_cols, bi_vals, E_bi, bundles, items, NB, NI, off_BI_b, off_BI_i);
    // UB: users + bundles, n_total = U+NB
    run_prop(ub_rows, ub_cols, ub_vals, E_ub, users, bundles, U, NB, off_UB_u, off_UB_b);
}

// Round 2
// 1414.709 us; speedup vs baseline: 1.4093x; 1.4093x over previous
//
#include <hip/hip_runtime.h>
#include <hip/hip_bf16.h>

// DSS bundle propagation: 3 graphs x (2-layer SpMM + L2norm + average).
// Strategy: on-device CSR build (count -> scan -> fill), gather-SpMM (one wave
// per row, lane = dim, register accumulate, single write per row), layer-2
// fused with the normalize/average/pack epilogue.
//
// Output rows: [UI_u(U) | UB_u(U) | BI_b(NB) | UB_b(NB) | UI_i(NI) | BI_i(NI)]

#define D 64

// ---------- CSR build ----------
__global__ void count_rows(const int* __restrict__ rows, int E, int* __restrict__ cnt) {
    int e = blockIdx.x * blockDim.x + threadIdx.x;
    if (e < E) atomicAdd(&cnt[rows[e]], 1);
}

// Per-256-block exclusive scan; row_ptr[i] = local exclusive, bsum[b] = block total.
__global__ void scan_block(const int* __restrict__ cnt, int n,
                           int* __restrict__ row_ptr, int* __restrict__ bsum) {
    __shared__ int s[256];
    int tid = threadIdx.x;
    int i = blockIdx.x * 256 + tid;
    int v = (i < n) ? cnt[i] : 0;
    s[tid] = v;
    __syncthreads();
    #pragma unroll
    for (int off = 1; off < 256; off <<= 1) {
        int t = (tid >= off) ? s[tid - off] : 0;
        __syncthreads();
        s[tid] += t;
        __syncthreads();
    }
    if (i < n) row_ptr[i] = s[tid] - v;           // exclusive within block
    if (tid == 255) bsum[blockIdx.x] = s[255];    // block total
}

// Single-block exclusive scan of block sums (nb <= ~1024s; loop with carry).
__global__ void scan_bsums(int* __restrict__ bsum, int nb) {
    __shared__ int s[1024];
    __shared__ int carry_s;
    int tid = threadIdx.x;
    if (tid == 0) carry_s = 0;
    __syncthreads();
    for (int base = 0; base < nb; base += 1024) {
        int i = base + tid;
        int v = (i < nb) ? bsum[i] : 0;
        s[tid] = v;
        __syncthreads();
        for (int off = 1; off < 1024; off <<= 1) {
            int t = (tid >= off) ? s[tid - off] : 0;
            __syncthreads();
            s[tid] += t;
            __syncthreads();
        }
        if (i < nb) bsum[i] = carry_s + s[tid] - v;  // exclusive
        __syncthreads();
        if (tid == 1023) carry_s += s[1023];
        __syncthreads();
    }
}

__global__ void add_offsets(int* __restrict__ row_ptr, const int* __restrict__ bsum,
                            int n, int E) {
    int i = blockIdx.x * blockDim.x + threadIdx.x;
    if (i < n) row_ptr[i] += bsum[i >> 8];
    if (i == 0) row_ptr[n] = E;
}

__global__ void fill_csr(const int* __restrict__ rows, const int* __restrict__ cols,
                         const float* __restrict__ vals, int E,
                         int* __restrict__ cursor,
                         int* __restrict__ csr_col, float* __restrict__ csr_val) {
    int e = blockIdx.x * blockDim.x + threadIdx.x;
    if (e < E) {
        int r = rows[e];
        int p = atomicAdd(&cursor[r], 1);
        csr_col[p] = cols[e];
        csr_val[p] = vals[e];
    }
}

// ---------- SpMM layer 1: f1[r] = sum_j v_j * feat[c_j], feat = concat(A,B) ----------
__global__ void spmm_l1(const int* __restrict__ row_ptr, const int* __restrict__ csr_col,
                        const float* __restrict__ csr_val,
                        const float* __restrict__ A, const float* __restrict__ B,
                        int nA, int n, float* __restrict__ f1) {
    long long t = (long long)blockIdx.x * blockDim.x + threadIdx.x;
    int r = (int)(t >> 6);
    int d = (int)(t & 63);
    if (r >= n) return;
    int beg = row_ptr[r], end = row_ptr[r + 1];
    float acc = 0.0f;
    for (int j = beg; j < end; ++j) {
        int c = csr_col[j];
        float v = csr_val[j];
        const float* src = (c < nA) ? (A + (long long)c * D) : (B + (long long)(c - nA) * D);
        acc += v * src[d];
    }
    f1[(long long)r * D + d] = acc;
}

// ---------- SpMM layer 2 fused with epilogue ----------
// acc = sum v * f1[c]; out = (feat0 + f1/||f1|| + acc/||acc||) / 3, packed.
__global__ void spmm_l2_fin(const int* __restrict__ row_ptr, const int* __restrict__ csr_col,
                            const float* __restrict__ csr_val,
                            const float* __restrict__ f1,
                            const float* __restrict__ A, const float* __restrict__ B,
                            int nA, int n, float* __restrict__ out,
                            long long offA, long long offB) {
    long long t = (long long)blockIdx.x * blockDim.x + threadIdx.x;
    int r = (int)(t >> 6);
    int d = (int)(t & 63);
    if (r >= n) return;
    int beg = row_ptr[r], end = row_ptr[r + 1];
    float acc = 0.0f;
    for (int j = beg; j < end; ++j) {
        int c = csr_col[j];
        float v = csr_val[j];
        acc += v * f1[(long long)c * D + d];
    }
    float x1 = f1[(long long)r * D + d];
    float s1 = x1 * x1;
    float s2 = acc * acc;
    #pragma unroll
    for (int m = 32; m > 0; m >>= 1) {
        s1 += __shfl_xor(s1, m, 64);
        s2 += __shfl_xor(s2, m, 64);
    }
    float n1 = fmaxf(sqrtf(s1), 1e-12f);
    float n2 = fmaxf(sqrtf(s2), 1e-12f);
    float x0 = (r < nA) ? A[(long long)r * D + d] : B[(long long)(r - nA) * D + d];
    float y = (x0 + x1 / n1 + acc / n2) * (1.0f / 3.0f);
    long long orow = (r < nA) ? (offA + r) : (offB + (r - nA));
    out[orow * D + d] = y;
}

extern "C" void kernel_launch(void* const* d_in, const int* in_sizes, int n_in,
                              void* d_out, int out_size, void* d_ws, size_t ws_size,
                              hipStream_t stream) {
    const float* users   = (const float*)d_in[0];
    const float* items   = (const float*)d_in[1];
    const float* bundles = (const float*)d_in[2];
    const float* ui_vals = (const float*)d_in[3];
    const float* bi_vals = (const float*)d_in[4];
    const float* ub_vals = (const float*)d_in[5];
    const int* ui_rows = (const int*)d_in[6];
    const int* ui_cols = (const int*)d_in[7];
    const int* bi_rows = (const int*)d_in[8];
    const int* bi_cols = (const int*)d_in[9];
    const int* ub_rows = (const int*)d_in[10];
    const int* ub_cols = (const int*)d_in[11];

    const int U  = in_sizes[0] / D;   // 100000
    const int NI = in_sizes[1] / D;   // 50000
    const int NB = in_sizes[2] / D;   // 20000
    const int E_ui = in_sizes[3];
    const int E_bi = in_sizes[4];
    const int E_ub = in_sizes[5];

    float* out = (float*)d_out;

    const int maxRows = U + NI;       // 150000
    const int maxE    = E_ui;         // 2M (largest)

    // Workspace layout (all 256-B aligned by construction of sizes)
    char* ws = (char*)d_ws;
    float* f1      = (float*)ws;                      ws += (size_t)maxRows * D * sizeof(float); // 38.4 MB
    int*   csr_col = (int*)ws;                        ws += (size_t)maxE * sizeof(int);          // 8 MB
    float* csr_val = (float*)ws;                      ws += (size_t)maxE * sizeof(float);        // 8 MB
    int*   row_ptr = (int*)ws;                        ws += (size_t)(maxRows + 1) * sizeof(int);
    int*   cursor  = (int*)ws;                        ws += (size_t)maxRows * sizeof(int);
    int*   bsum    = (int*)ws;                        ws += 1024 * sizeof(int);
    (void)ws_size;

    // Output row offsets
    const long long off_UI_u = 0;
    const long long off_UB_u = U;
    const long long off_BI_b = 2LL * U;
    const long long off_UB_b = 2LL * U + NB;
    const long long off_UI_i = 2LL * U + 2LL * NB;
    const long long off_BI_i = 2LL * U + 2LL * NB + NI;

    auto run_prop = [&](const int* rows, const int* cols, const float* vals, int E,
                        const float* A, const float* B, int nA, int nB,
                        long long offA, long long offB) {
        const int n = nA + nB;
        const int eblocks = (E + 255) / 256;
        const int nblocks = (n + 255) / 256;

        // --- CSR build ---
        hipMemsetAsync(cursor, 0, (size_t)n * sizeof(int), stream);   // reuse cursor as cnt
        count_rows<<<eblocks, 256, 0, stream>>>(rows, E, cursor);
        scan_block<<<nblocks, 256, 0, stream>>>(cursor, n, row_ptr, bsum);
        scan_bsums<<<1, 1024, 0, stream>>>(bsum, nblocks);
        add_offsets<<<nblocks, 256, 0, stream>>>(row_ptr, bsum, n, E);
        hipMemcpyAsync(cursor, row_ptr, (size_t)n * sizeof(int),
                       hipMemcpyDeviceToDevice, stream);
        fill_csr<<<eblocks, 256, 0, stream>>>(rows, cols, vals, E, cursor, csr_col, csr_val);

        // --- 2-layer propagation ---
        const long long T = (long long)n * D;
        const int rblocks = (int)((T + 255) / 256);
        spmm_l1<<<rblocks, 256, 0, stream>>>(row_ptr, csr_col, csr_val, A, B, nA, n, f1);
        spmm_l2_fin<<<rblocks, 256, 0, stream>>>(row_ptr, csr_col, csr_val, f1,
                                                 A, B, nA, n, out, offA, offB);
    };

    run_prop(ui_rows, ui_cols, ui_vals, E_ui, users, items, U, NI, off_UI_u, off_UI_i);
    run_prop(bi_rows, bi_cols, bi_vals, E_bi, bundles, items, NB, NI, off_BI_b, off_BI_i);
    run_prop(ub_rows, ub_cols, ub_vals, E_ub, users, bundles, U, NB, off_UB_u, off_UB_b);
}

// Round 3
// 1038.729 us; speedup vs baseline: 1.9194x; 1.3620x over previous
//
#include <hip/hip_runtime.h>
#include <hip/hip_bf16.h>

// DSS bundle propagation: 3 graphs x (2-layer SpMM + L2norm + average).
// R2: gather-SpMM with 4-deep software-pipelined edge loop + packed (col,val)
// int2 edge records to break the per-edge dependent-load chain (latency-bound
// at 246 cyc/edge in R1 counters).
//
// Output rows: [UI_u(U) | UB_u(U) | BI_b(NB) | UB_b(NB) | UI_i(NI) | BI_i(NI)]

#define D 64

// ---------- CSR build ----------
__global__ void count_rows(const int* __restrict__ rows, int E, int* __restrict__ cnt) {
    int e = blockIdx.x * blockDim.x + threadIdx.x;
    if (e < E) atomicAdd(&cnt[rows[e]], 1);
}

__global__ void scan_block(const int* __restrict__ cnt, int n,
                           int* __restrict__ row_ptr, int* __restrict__ bsum) {
    __shared__ int s[256];
    int tid = threadIdx.x;
    int i = blockIdx.x * 256 + tid;
    int v = (i < n) ? cnt[i] : 0;
    s[tid] = v;
    __syncthreads();
    #pragma unroll
    for (int off = 1; off < 256; off <<= 1) {
        int t = (tid >= off) ? s[tid - off] : 0;
        __syncthreads();
        s[tid] += t;
        __syncthreads();
    }
    if (i < n) row_ptr[i] = s[tid] - v;
    if (tid == 255) bsum[blockIdx.x] = s[255];
}

__global__ void scan_bsums(int* __restrict__ bsum, int nb) {
    __shared__ int s[1024];
    __shared__ int carry_s;
    int tid = threadIdx.x;
    if (tid == 0) carry_s = 0;
    __syncthreads();
    for (int base = 0; base < nb; base += 1024) {
        int i = base + tid;
        int v = (i < nb) ? bsum[i] : 0;
        s[tid] = v;
        __syncthreads();
        for (int off = 1; off < 1024; off <<= 1) {
            int t = (tid >= off) ? s[tid - off] : 0;
            __syncthreads();
            s[tid] += t;
            __syncthreads();
        }
        if (i < nb) bsum[i] = carry_s + s[tid] - v;
        __syncthreads();
        if (tid == 1023) carry_s += s[1023];
        __syncthreads();
    }
}

__global__ void add_offsets(int* __restrict__ row_ptr, const int* __restrict__ bsum,
                            int n, int E) {
    int i = blockIdx.x * blockDim.x + threadIdx.x;
    if (i < n) row_ptr[i] += bsum[i >> 8];
    if (i == 0) row_ptr[n] = E;
}

// Packed edge record: .x = col, .y = bit-cast float val
__global__ void fill_csr(const int* __restrict__ rows, const int* __restrict__ cols,
                         const float* __restrict__ vals, int E,
                         int* __restrict__ cursor, int2* __restrict__ ev) {
    int e = blockIdx.x * blockDim.x + threadIdx.x;
    if (e < E) {
        int r = rows[e];
        int p = atomicAdd(&cursor[r], 1);
        ev[p] = make_int2(cols[e], __float_as_int(vals[e]));
    }
}

// ---------- SpMM layer 1 (4-deep pipelined) ----------
__global__ void spmm_l1(const int* __restrict__ row_ptr, const int2* __restrict__ ev,
                        const float* __restrict__ A, const float* __restrict__ B,
                        int nA, int n, float* __restrict__ f1) {
    long long t = (long long)blockIdx.x * blockDim.x + threadIdx.x;
    int r = (int)(t >> 6);
    int d = (int)(t & 63);
    if (r >= n) return;
    int beg = row_ptr[r], end = row_ptr[r + 1];
    float acc = 0.0f;
    int j = beg;
    for (; j + 4 <= end; j += 4) {
        int2 e0 = ev[j], e1 = ev[j + 1], e2 = ev[j + 2], e3 = ev[j + 3];
        const float* p0 = (e0.x < nA) ? A + (size_t)e0.x * D : B + (size_t)(e0.x - nA) * D;
        const float* p1 = (e1.x < nA) ? A + (size_t)e1.x * D : B + (size_t)(e1.x - nA) * D;
        const float* p2 = (e2.x < nA) ? A + (size_t)e2.x * D : B + (size_t)(e2.x - nA) * D;
        const float* p3 = (e3.x < nA) ? A + (size_t)e3.x * D : B + (size_t)(e3.x - nA) * D;
        float x0 = p0[d], x1 = p1[d], x2 = p2[d], x3 = p3[d];
        acc = fmaf(__int_as_float(e0.y), x0, acc);
        acc = fmaf(__int_as_float(e1.y), x1, acc);
        acc = fmaf(__int_as_float(e2.y), x2, acc);
        acc = fmaf(__int_as_float(e3.y), x3, acc);
    }
    for (; j < end; ++j) {
        int2 e = ev[j];
        const float* p = (e.x < nA) ? A + (size_t)e.x * D : B + (size_t)(e.x - nA) * D;
        acc = fmaf(__int_as_float(e.y), p[d], acc);
    }
    f1[(size_t)r * D + d] = acc;
}

// ---------- SpMM layer 2 fused with epilogue (4-deep pipelined) ----------
__global__ void spmm_l2_fin(const int* __restrict__ row_ptr, const int2* __restrict__ ev,
                            const float* __restrict__ f1,
                            const float* __restrict__ A, const float* __restrict__ B,
                            int nA, int n, float* __restrict__ out,
                            long long offA, long long offB) {
    long long t = (long long)blockIdx.x * blockDim.x + threadIdx.x;
    int r = (int)(t >> 6);
    int d = (int)(t & 63);
    if (r >= n) return;
    int beg = row_ptr[r], end = row_ptr[r + 1];
    float acc = 0.0f;
    int j = beg;
    for (; j + 4 <= end; j += 4) {
        int2 e0 = ev[j], e1 = ev[j + 1], e2 = ev[j + 2], e3 = ev[j + 3];
        float x0 = f1[(size_t)e0.x * D + d];
        float x1 = f1[(size_t)e1.x * D + d];
        float x2 = f1[(size_t)e2.x * D + d];
        float x3 = f1[(size_t)e3.x * D + d];
        acc = fmaf(__int_as_float(e0.y), x0, acc);
        acc = fmaf(__int_as_float(e1.y), x1, acc);
        acc = fmaf(__int_as_float(e2.y), x2, acc);
        acc = fmaf(__int_as_float(e3.y), x3, acc);
    }
    for (; j < end; ++j) {
        int2 e = ev[j];
        acc = fmaf(__int_as_float(e.y), f1[(size_t)e.x * D + d], acc);
    }
    float x1r = f1[(size_t)r * D + d];
    float s1 = x1r * x1r;
    float s2 = acc * acc;
    #pragma unroll
    for (int m = 32; m > 0; m >>= 1) {
        s1 += __shfl_xor(s1, m, 64);
        s2 += __shfl_xor(s2, m, 64);
    }
    float n1 = fmaxf(sqrtf(s1), 1e-12f);
    float n2 = fmaxf(sqrtf(s2), 1e-12f);
    float x0 = (r < nA) ? A[(size_t)r * D + d] : B[(size_t)(r - nA) * D + d];
    float y = (x0 + x1r / n1 + acc / n2) * (1.0f / 3.0f);
    long long orow = (r < nA) ? (offA + r) : (offB + (r - nA));
    out[orow * D + d] = y;
}

extern "C" void kernel_launch(void* const* d_in, const int* in_sizes, int n_in,
                              void* d_out, int out_size, void* d_ws, size_t ws_size,
                              hipStream_t stream) {
    const float* users   = (const float*)d_in[0];
    const float* items   = (const float*)d_in[1];
    const float* bundles = (const float*)d_in[2];
    const float* ui_vals = (const float*)d_in[3];
    const float* bi_vals = (const float*)d_in[4];
    const float* ub_vals = (const float*)d_in[5];
    const int* ui_rows = (const int*)d_in[6];
    const int* ui_cols = (const int*)d_in[7];
    const int* bi_rows = (const int*)d_in[8];
    const int* bi_cols = (const int*)d_in[9];
    const int* ub_rows = (const int*)d_in[10];
    const int* ub_cols = (const int*)d_in[11];

    const int U  = in_sizes[0] / D;
    const int NI = in_sizes[1] / D;
    const int NB = in_sizes[2] / D;
    const int E_ui = in_sizes[3];
    const int E_bi = in_sizes[4];
    const int E_ub = in_sizes[5];

    float* out = (float*)d_out;

    const int maxRows = U + NI;       // 150000
    const int maxE    = E_ui;         // 2M

    char* ws = (char*)d_ws;
    float* f1      = (float*)ws;  ws += (size_t)maxRows * D * sizeof(float); // 38.4 MB
    int2*  ev      = (int2*)ws;   ws += (size_t)maxE * sizeof(int2);         // 16 MB
    int*   row_ptr = (int*)ws;    ws += (size_t)(maxRows + 1) * sizeof(int);
    int*   cursor  = (int*)ws;    ws += (size_t)maxRows * sizeof(int);
    int*   bsum    = (int*)ws;    ws += 1024 * sizeof(int);
    (void)ws_size;

    const long long off_UI_u = 0;
    const long long off_UB_u = U;
    const long long off_BI_b = 2LL * U;
    const long long off_UB_b = 2LL * U + NB;
    const long long off_UI_i = 2LL * U + 2LL * NB;
    const long long off_BI_i = 2LL * U + 2LL * NB + NI;

    auto run_prop = [&](const int* rows, const int* cols, const float* vals, int E,
                        const float* A, const float* B, int nA, int nB,
                        long long offA, long long offB) {
        const int n = nA + nB;
        const int eblocks = (E + 255) / 256;
        const int nblocks = (n + 255) / 256;

        hipMemsetAsync(cursor, 0, (size_t)n * sizeof(int), stream);
        count_rows<<<eblocks, 256, 0, stream>>>(rows, E, cursor);
        scan_block<<<nblocks, 256, 0, stream>>>(cursor, n, row_ptr, bsum);
        scan_bsums<<<1, 1024, 0, stream>>>(bsum, nblocks);
        add_offsets<<<nblocks, 256, 0, stream>>>(row_ptr, bsum, n, E);
        hipMemcpyAsync(cursor, row_ptr, (size_t)n * sizeof(int),
                       hipMemcpyDeviceToDevice, stream);
        fill_csr<<<eblocks, 256, 0, stream>>>(rows, cols, vals, E, cursor, ev);

        const long long T = (long long)n * D;
        const int rblocks = (int)((T + 255) / 256);
        spmm_l1<<<rblocks, 256, 0, stream>>>(row_ptr, ev, A, B, nA, n, f1);
        spmm_l2_fin<<<rblocks, 256, 0, stream>>>(row_ptr, ev, f1, A, B, nA, n,
                                                 out, offA, offB);
    };

    run_prop(ui_rows, ui_cols, ui_vals, E_ui, users, items, U, NI, off_UI_u, off_UI_i);
    run_prop(bi_rows, bi_cols, bi_vals, E_bi, bundles, items, NB, NI, off_BI_b, off_BI_i);
    run_prop(ub_rows, ub_cols, ub_vals, E_ub, users, bundles, U, NB, off_UB_u, off_UB_b);
}